// Round 5
// baseline (529.288 us; speedup 1.0000x reference)
//
#include <hip/hip_runtime.h>
#include <math.h>

// Problem constants
#define NTOT 4096        // H*W = 64*64
#define NBATCH 8
#define CIN 128
#define CK 64
#define CV 64
#define CO 128
#define BN_COUNT 32768.0f // B*H*W

// Workspace layout (float offsets).
#define OFF_YQ    0ul
#define OFF_YK    2097152ul
#define OFF_V     4194304ul
#define OFF_STATS 6291456ul   // [which(2)][sum/sumsq(2)][64] = 256
#define OFF_KV    6291712ul   // [8][64][64] = 32768
#define OFF_VSUM  6324480ul   // [8][64] = 512
#define OFF_M     6324992ul   // [8][64][128] (c,o) = 65536
#define OFF_D     6390528ul   // [8][128] = 1024
#define ZERO_FLOATS (256 + 32768 + 512)   // stats + KV + vsum, contiguous

// ---------------------------------------------------------------------------
// Kernel 1 (v5): 1x1 conv GEMM + fused BN-stats/vsum.
// grid (64 n-chunks, 8 batch, 3 tensors) = 1536 blocks, block 256.
// NO barriers / NO LDS in the K-loop: W (32 KB) staged once; wave w owns
// o in [16w,16w+16) -> W ds_read_b128 are full-wave broadcasts (free);
// lane owns one n-column, X streamed from global (coalesced dword loads,
// 128 independent loads/thread). 5 blocks/CU (LDS-capped).
// ---------------------------------------------------------------------------
__global__ __launch_bounds__(256, 5) void gemm3_kernel(
    const float* __restrict__ Xq, const float* __restrict__ Xk, const float* __restrict__ Xv,
    const float* __restrict__ Wk, const float* __restrict__ bk,
    const float* __restrict__ Wv, const float* __restrict__ bv,
    float* __restrict__ Yq, float* __restrict__ Yk, float* __restrict__ Vv,
    float* __restrict__ stats, float* __restrict__ vsum)
{
    const int chunk = blockIdx.x;           // 0..63
    const int b     = blockIdx.y;
    const int which = blockIdx.z;
    const float* X    = (which == 0) ? Xq : (which == 1) ? Xk : Xv;
    const float* W    = (which == 2) ? Wv : Wk;
    const float* bias = (which == 2) ? bv : bk;
    float* Y          = (which == 0) ? Yq : (which == 1) ? Yk : Vv;

    __shared__ float sW[CK * CIN];   // [o][k] natural, 32 KB

    const int t    = threadIdx.x;
    const int wv   = t >> 6;         // wave 0..3 -> o base 16*wv (wave-uniform)
    const int lane = t & 63;
    const int n    = chunk * 64 + lane;

    // Stage W once: 2048 float4, consecutive -> conflict-free.
#pragma unroll
    for (int r = 0; r < 8; ++r) {
        int idx4 = t + r * 256;          // 0..2047
        int o  = idx4 >> 5;              // 0..63
        int c4 = (idx4 & 31) << 2;       // 0..124
        *(float4*)&sW[o * CIN + c4] = *(const float4*)(W + (size_t)o * CIN + c4);
    }
    __syncthreads();

    const float* Xcol = X + (size_t)b * (CIN * NTOT) + n;
    float acc[16];
#pragma unroll
    for (int i = 0; i < 16; ++i) acc[i] = 0.f;

#pragma unroll 4
    for (int kk = 0; kk < 32; ++kk) {    // 4 k per iter
        float x0 = Xcol[(size_t)(kk * 4 + 0) * NTOT];
        float x1 = Xcol[(size_t)(kk * 4 + 1) * NTOT];
        float x2 = Xcol[(size_t)(kk * 4 + 2) * NTOT];
        float x3 = Xcol[(size_t)(kk * 4 + 3) * NTOT];
#pragma unroll
        for (int i = 0; i < 16; ++i) {
            float4 wf = *(const float4*)&sW[(wv * 16 + i) * CIN + kk * 4]; // broadcast
            acc[i] += wf.x * x0 + wf.y * x1 + wf.z * x2 + wf.w * x3;
        }
    }

    // epilogue: bias + coalesced store
    float* Yb = Y + (size_t)b * (CK * NTOT) + chunk * 64 + lane;
#pragma unroll
    for (int i = 0; i < 16; ++i) {
        acc[i] += bias[wv * 16 + i];
        Yb[(size_t)(wv * 16 + i) * NTOT] = acc[i];
    }

    // fused reductions: wave w owns channels 16w..16w+15 over its 64 columns.
    if (which < 2) {
        float s[16], ss[16];
#pragma unroll
        for (int i = 0; i < 16; ++i) { s[i] = acc[i]; ss[i] = acc[i] * acc[i]; }
#pragma unroll
        for (int off = 32; off > 0; off >>= 1)
#pragma unroll
            for (int i = 0; i < 16; ++i) {
                s[i]  += __shfl_down(s[i],  off, 64);
                ss[i] += __shfl_down(ss[i], off, 64);
            }
        if (lane == 0) {
#pragma unroll
            for (int i = 0; i < 16; ++i) {
                atomicAdd(&stats[which * 128 + wv * 16 + i], s[i]);
                atomicAdd(&stats[which * 128 + 64 + wv * 16 + i], ss[i]);
            }
        }
    } else {
        float s[16];
#pragma unroll
        for (int i = 0; i < 16; ++i) s[i] = acc[i];
#pragma unroll
        for (int off = 32; off > 0; off >>= 1)
#pragma unroll
            for (int i = 0; i < 16; ++i)
                s[i] += __shfl_down(s[i], off, 64);
        if (lane == 0) {
#pragma unroll
            for (int i = 0; i < 16; ++i)
                atomicAdd(&vsum[b * CV + wv * 16 + i], s[i]);
        }
    }
}

// ---------------------------------------------------------------------------
// Kernel 2: KV[b,c,v] = sum_n kn[b,c,n]*V[b,v,n], kn = L2-norm(BN(Yk)).
// grid (128 n-chunks of 32, 8 batch) = 1024 blocks (4/CU), split-K atomics.
// Pad 37 (37%32=5): j-loop b32 reads ~2-way, staging ~2-way.
// ---------------------------------------------------------------------------
#define KVP 37
__global__ __launch_bounds__(256, 4) void kv_kernel(
    const float* __restrict__ Yk, const float* __restrict__ Vv,
    const float* __restrict__ stats,
    const float* __restrict__ gamma, const float* __restrict__ beta,
    float* __restrict__ KV)
{
    const int chunk = blockIdx.x;    // 0..127
    const int b     = blockIdx.y;
    __shared__ float sk[64 * KVP];
    __shared__ float sv[64 * KVP];
    __shared__ float rnp[8][32];
    __shared__ float rn[32];
    __shared__ float kscl[64], kshf[64];

    const int t = threadIdx.x;
    if (t < 64) {
        float S = stats[128 + t], SS = stats[192 + t];
        float mean = S * (1.f / BN_COUNT);
        float var  = SS * (1.f / BN_COUNT) - mean * mean;
        float scl = gamma[t] * rsqrtf(var + 1e-5f);
        kscl[t] = scl;
        kshf[t] = beta[t] - mean * scl;
    }
    __syncthreads();

    const int n0 = chunk * 32;
    const float* Ykb = Yk + (size_t)b * (CK * NTOT) + n0;
    const float* Vb  = Vv + (size_t)b * (CK * NTOT) + n0;

#pragma unroll
    for (int r = 0; r < 2; ++r) {
        int idx4 = t + r * 256;          // 0..511 = 64 c x 8 j4
        int c  = idx4 >> 3;
        int j4 = (idx4 & 7) << 2;
        float4 kf = *(const float4*)(Ykb + (size_t)c * NTOT + j4);
        float4 vf = *(const float4*)(Vb  + (size_t)c * NTOT + j4);
        float scl = kscl[c], sh = kshf[c];
        sk[c * KVP + j4 + 0] = kf.x * scl + sh;
        sk[c * KVP + j4 + 1] = kf.y * scl + sh;
        sk[c * KVP + j4 + 2] = kf.z * scl + sh;
        sk[c * KVP + j4 + 3] = kf.w * scl + sh;
        sv[c * KVP + j4 + 0] = vf.x; sv[c * KVP + j4 + 1] = vf.y;
        sv[c * KVP + j4 + 2] = vf.z; sv[c * KVP + j4 + 3] = vf.w;
    }
    __syncthreads();
    {   // column sumsq partials: half-wave hw covers c in [8hw, 8hw+8)
        int nn = t & 31, hw = t >> 5;
        float ps = 0.f;
#pragma unroll
        for (int i = 0; i < 8; ++i) {
            float x = sk[(hw * 8 + i) * KVP + nn];
            ps += x * x;
        }
        rnp[hw][nn] = ps;
    }
    __syncthreads();
    if (t < 32) {
        float rs = 0.f;
#pragma unroll
        for (int i = 0; i < 8; ++i) rs += rnp[i][t];
        rn[t] = 1.f / (sqrtf(rs) + 1e-7f);
    }
    __syncthreads();

    const int tc = t >> 4, tv = t & 15;
    float acc[4][4];
#pragma unroll
    for (int i = 0; i < 4; ++i)
#pragma unroll
        for (int k2 = 0; k2 < 4; ++k2) acc[i][k2] = 0.f;

#pragma unroll 4
    for (int j = 0; j < 32; ++j) {
        float arn = rn[j];
        float a[4], bb[4];
#pragma unroll
        for (int i = 0; i < 4; ++i) a[i]  = sk[(tc * 4 + i) * KVP + j] * arn;
#pragma unroll
        for (int i = 0; i < 4; ++i) bb[i] = sv[(tv * 4 + i) * KVP + j];
#pragma unroll
        for (int i = 0; i < 4; ++i)
#pragma unroll
            for (int k2 = 0; k2 < 4; ++k2) acc[i][k2] += a[i] * bb[k2];
    }

    float* KVb = KV + b * (CK * CV);
#pragma unroll
    for (int i = 0; i < 4; ++i)
#pragma unroll
        for (int k2 = 0; k2 < 4; ++k2)
            atomicAdd(&KVb[(tc * 4 + i) * CV + tv * 4 + k2], acc[i][k2]);
}

// ---------------------------------------------------------------------------
// Kernel 3: M[b,c,o] = sum_v KV[b,c,v]*Ww[o,v];  d[b,o] = bw[o] + Ww·vsum
// grid (8 o-slices, 8 batch), block 256; each block: 64c x 16o.
// ---------------------------------------------------------------------------
__global__ __launch_bounds__(256) void m_kernel(
    const float* __restrict__ KV, const float* __restrict__ vsum,
    const float* __restrict__ Ww, const float* __restrict__ bw,
    float* __restrict__ M, float* __restrict__ d)
{
    const int och = blockIdx.x;       // 0..7, o-slice of 16
    const int b   = blockIdx.y;
    __shared__ float sKV[64 * 65];
    __shared__ float sWw[16 * 68];
    __shared__ float svs[64];
    const int t = threadIdx.x;

#pragma unroll
    for (int r = 0; r < 16; ++r) {
        int idx = t + r * 256;                       // 0..4095
        sKV[(idx >> 6) * 65 + (idx & 63)] = KV[b * (CK * CV) + idx];
    }
    {   // 16 o-rows x 64 v = 256 float4
        int o16 = t >> 4, v4 = (t & 15) << 2;
        float4 wv = *(const float4*)(Ww + (size_t)(och * 16 + o16) * CV + v4);
        *(float4*)&sWw[o16 * 68 + v4] = wv;
    }
    if (t < 64) svs[t] = vsum[b * CV + t];
    __syncthreads();

#pragma unroll
    for (int r = 0; r < 4; ++r) {
        int idx = t + r * 256;                       // 0..1023
        int c = idx >> 4, o16 = idx & 15;
        float acc = 0.f;
#pragma unroll 16
        for (int v = 0; v < 64; ++v) acc += sKV[c * 65 + v] * sWw[o16 * 68 + v];
        M[(size_t)b * (CK * CO) + (size_t)c * CO + och * 16 + o16] = acc;
    }
    if (t < 16) {
        int o = och * 16 + t;
        float acc = bw[o];
#pragma unroll 16
        for (int v = 0; v < 64; ++v) acc += sWw[t * 68 + v] * svs[v];
        d[b * CO + o] = acc;
    }
}

// ---------------------------------------------------------------------------
// Kernel 4: out[b,o,n] = rn_n * (sum_c qhat[b,c,n]*M[b,c,o]) + d[b,o]
// qhat = BN(Yq); rn applied in epilogue. o split in halves of 64.
// grid (64 n-chunks, 2 o-halves, 8 batch) = 1024 blocks (4/CU). Thread: 4n x 4o.
// ---------------------------------------------------------------------------
__global__ __launch_bounds__(256, 4) void out_kernel(
    const float* __restrict__ Yq,
    const float* __restrict__ stats,
    const float* __restrict__ gamma, const float* __restrict__ beta,
    const float* __restrict__ M, const float* __restrict__ d,
    float* __restrict__ out)
{
    const int chunk = blockIdx.x;
    const int oh    = blockIdx.y;    // 0/1, o-half of 64
    const int b     = blockIdx.z;
    __shared__ float sM[CK * 64];     // [c][o-half], 16 KB
    __shared__ float sq[64 * 68];     // padded rows
    __shared__ float rnp[4][64];
    __shared__ float sd[64];
    __shared__ float qscl[64], qshf[64];

    const int t = threadIdx.x;
    const int n0 = chunk * 64;

    if (t < 64) {
        float S = stats[t], SS = stats[64 + t];
        float mean = S * (1.f / BN_COUNT);
        float var  = SS * (1.f / BN_COUNT) - mean * mean;
        float scl = gamma[t] * rsqrtf(var + 1e-5f);
        qscl[t] = scl;
        qshf[t] = beta[t] - mean * scl;
        sd[t] = d[b * CO + oh * 64 + t];
    }
    __syncthreads();

    // stage M half: 64c x 64o -> 1024 float4
#pragma unroll
    for (int r = 0; r < 4; ++r) {
        int idx4 = t + r * 256;
        int c  = idx4 >> 4;
        int o4 = (idx4 & 15) << 2;
        *(float4*)&sM[c * 64 + o4] =
            *(const float4*)(M + (size_t)b * (CK * CO) + (size_t)c * CO + oh * 64 + o4);
    }
    const float* Yb = Yq + (size_t)b * (CK * NTOT) + n0;
#pragma unroll
    for (int r = 0; r < 4; ++r) {
        int idx4 = t + r * 256;
        int c  = idx4 >> 4;
        int j4 = (idx4 & 15) << 2;
        float4 xv = *(const float4*)(Yb + (size_t)c * NTOT + j4);
        float scl = qscl[c], sh = qshf[c];
        *(float4*)&sq[c * 68 + j4] = make_float4(
            xv.x * scl + sh, xv.y * scl + sh, xv.z * scl + sh, xv.w * scl + sh);
    }
    __syncthreads();
    {   // column sumsq partials across 4 waves
        int nn = t & 63, w = t >> 6;
        float ps = 0.f;
#pragma unroll
        for (int i = 0; i < 16; ++i) {
            float x = sq[(w * 16 + i) * 68 + nn];
            ps += x * x;
        }
        rnp[w][nn] = ps;
    }
    __syncthreads();

    const int j0 = (t & 15) << 2;       // 4 columns
    const int o0 = (t >> 4) << 2;       // 4 o within half
    float acc[4][4];
#pragma unroll
    for (int jj = 0; jj < 4; ++jj)
#pragma unroll
        for (int oo = 0; oo < 4; ++oo) acc[jj][oo] = 0.f;

#pragma unroll 4
    for (int c = 0; c < 64; ++c) {
        float4 qv = *(const float4*)&sq[c * 68 + j0];
        float4 mv = *(const float4*)&sM[c * 64 + o0];
        float aq[4] = {qv.x, qv.y, qv.z, qv.w};
        float am[4] = {mv.x, mv.y, mv.z, mv.w};
#pragma unroll
        for (int jj = 0; jj < 4; ++jj)
#pragma unroll
            for (int oo = 0; oo < 4; ++oo) acc[jj][oo] += aq[jj] * am[oo];
    }

    float rnj[4];
#pragma unroll
    for (int jj = 0; jj < 4; ++jj) {
        int j = j0 + jj;
        float rs = rnp[0][j] + rnp[1][j] + rnp[2][j] + rnp[3][j];
        rnj[jj] = 1.f / (sqrtf(rs) + 1e-7f);
    }
    float* outb = out + (size_t)b * (CO * NTOT) + (size_t)(oh * 64) * NTOT + n0;
#pragma unroll
    for (int oo = 0; oo < 4; ++oo) {
        float dv = sd[o0 + oo];
        float4 st = make_float4(acc[0][oo] * rnj[0] + dv, acc[1][oo] * rnj[1] + dv,
                                acc[2][oo] * rnj[2] + dv, acc[3][oo] * rnj[3] + dv);
        *(float4*)&outb[(size_t)(o0 + oo) * NTOT + j0] = st;
    }
}

// ---------------------------------------------------------------------------
extern "C" void kernel_launch(void* const* d_in, const int* in_sizes, int n_in,
                              void* d_out, int out_size, void* d_ws, size_t ws_size,
                              hipStream_t stream) {
    (void)in_sizes; (void)n_in; (void)out_size; (void)ws_size;
    const float* q     = (const float*)d_in[0];
    const float* k     = (const float*)d_in[1];
    const float* v     = (const float*)d_in[2];
    const float* Wk    = (const float*)d_in[3];
    const float* bk    = (const float*)d_in[4];
    const float* gamma = (const float*)d_in[5];
    const float* beta  = (const float*)d_in[6];
    const float* Wv    = (const float*)d_in[7];
    const float* bv    = (const float*)d_in[8];
    const float* Ww    = (const float*)d_in[9];
    const float* bw    = (const float*)d_in[10];
    float* out = (float*)d_out;
    float* ws  = (float*)d_ws;

    float* Yq    = ws + OFF_YQ;
    float* Yk    = ws + OFF_YK;
    float* Vv    = ws + OFF_V;
    float* stats = ws + OFF_STATS;
    float* KV    = ws + OFF_KV;
    float* vsum  = ws + OFF_VSUM;
    float* M     = ws + OFF_M;
    float* dd    = ws + OFF_D;

    // zero stats + KV + vsum (contiguous; ws is re-poisoned before every call)
    hipMemsetAsync(stats, 0, ZERO_FLOATS * sizeof(float), stream);

    gemm3_kernel<<<dim3(64, NBATCH, 3), 256, 0, stream>>>(
        q, k, v, Wk, bk, Wv, bv, Yq, Yk, Vv, stats, vsum);
    kv_kernel<<<dim3(128, NBATCH), 256, 0, stream>>>(Yk, Vv, stats, gamma, beta, KV);
    m_kernel<<<dim3(8, NBATCH), 256, 0, stream>>>(KV, vsum, Ww, bw, M, dd);
    out_kernel<<<dim3(64, 2, NBATCH), 256, 0, stream>>>(Yq, stats, gamma, beta, M, dd, out);
}

// Round 7
// 349.387 us; speedup vs baseline: 1.5149x; 1.5149x over previous
//
#include <hip/hip_runtime.h>
#include <math.h>

// Problem constants
#define NTOT 4096        // H*W = 64*64
#define NBATCH 8
#define CIN 128
#define CK 64
#define CV 64
#define CO 128
#define BN_COUNT 32768.0f // B*H*W

// Workspace layout (float offsets).
#define OFF_YQ    0ul
#define OFF_YK    2097152ul
#define OFF_V     4194304ul
#define OFF_STATS 6291456ul   // [which(2)][sum/sumsq(2)][64] = 256
#define OFF_KV    6291712ul   // [8][64][64] = 32768
#define OFF_VSUM  6324480ul   // [8][64] = 512
#define OFF_M     6324992ul   // [8][64][128] (c,o) = 65536
#define OFF_D     6390528ul   // [8][128] = 1024
#define ZERO_FLOATS (256 + 32768 + 512)   // stats + KV + vsum, contiguous

// Async global->LDS, 16 B per lane. LDS dest collapses to first-lane base +
// lane*16, which matches our contiguous lane-order layout exactly.
__device__ __forceinline__ void gl2lds16(const float* g, float* l) {
    __builtin_amdgcn_global_load_lds(
        (const __attribute__((address_space(1))) unsigned int*)g,
        (__attribute__((address_space(3))) unsigned int*)l,
        16, 0, 0);
}

// ---------------------------------------------------------------------------
// Kernel 1 (v6b): 1x1 conv GEMM + fused BN-stats/vsum.
// grid (32 n-chunks x 2 o-halves, 8 batch, 3 tensors) = 1536 blocks, 256 thr.
// Block tile: 32 o x 128 n. W-half (16 KB) staged once via global_load_lds;
// X double-buffered (2 x 32k x 128n = 32 KB): DMA chunk k+1 issued BEFORE
// computing chunk k, so the vmcnt drain at the barrier is already satisfied.
// Thread: 8 o x 2 n. W ds_read_b128 = full-wave broadcast (o base = wave id);
// X ds_read_b64 contiguous. 48 KB LDS -> 3 blocks/CU.
// ---------------------------------------------------------------------------
__global__ __launch_bounds__(256) void gemm3_kernel(
    const float* __restrict__ Xq, const float* __restrict__ Xk, const float* __restrict__ Xv,
    const float* __restrict__ Wk, const float* __restrict__ bk,
    const float* __restrict__ Wv, const float* __restrict__ bv,
    float* __restrict__ Yq, float* __restrict__ Yk, float* __restrict__ Vv,
    float* __restrict__ stats, float* __restrict__ vsum)
{
    const int nchunk = blockIdx.x >> 1;     // 0..31
    const int oh     = blockIdx.x & 1;      // o-half
    const int b      = blockIdx.y;
    const int which  = blockIdx.z;
    const float* X    = (which == 0) ? Xq : (which == 1) ? Xk : Xv;
    const float* W    = (which == 2) ? Wv : Wk;
    const float* bias = (which == 2) ? bv : bk;
    float* Y          = (which == 0) ? Yq : (which == 1) ? Yk : Vv;

    __shared__ float sW[32 * 128];      // [o-half][k], 16 KB, natural layout
    __shared__ float sX[2 * 32 * 128];  // [buf][k][n], 2 x 16 KB

    const int t    = threadIdx.x;
    const int wv   = t >> 6;            // wave 0..3 -> o-octet (wave-uniform)
    const int lane = t & 63;
    const int n0   = lane << 1;         // 0..126
    const int nblk = nchunk * 128;
    const int ob   = wv * 8;            // o base within half

    const float* Xb = X + (size_t)b * (CIN * NTOT) + nblk;
    const float* Wb = W + (size_t)(oh * 32) * CIN;

    // stage W-half (1024 float4) + X chunk 0 (1024 float4), all async DMA
#pragma unroll
    for (int r = 0; r < 4; ++r) {
        int idx4 = t + r * 256;          // 0..1023
        gl2lds16(Wb + (size_t)(idx4 >> 5) * CIN + ((idx4 & 31) << 2), sW + idx4 * 4);
    }
#pragma unroll
    for (int r = 0; r < 4; ++r) {
        int idx4 = t + r * 256;
        gl2lds16(Xb + (size_t)(idx4 >> 5) * NTOT + ((idx4 & 31) << 2), sX + idx4 * 4);
    }
    __syncthreads();   // vmcnt(0) drain of the staging DMAs

    float acc[8][2];
#pragma unroll
    for (int o = 0; o < 8; ++o) { acc[o][0] = 0.f; acc[o][1] = 0.f; }

    for (int ck = 0; ck < 4; ++ck) {
        // prefetch next chunk into the other buffer (drained at the barrier
        // AFTER this chunk's compute — a full compute phase to cover latency)
        if (ck < 3) {
            float* dst = sX + ((ck + 1) & 1) * 4096;
            const float* src = Xb + (size_t)((ck + 1) * 32) * NTOT;
#pragma unroll
            for (int r = 0; r < 4; ++r) {
                int idx4 = t + r * 256;
                gl2lds16(src + (size_t)(idx4 >> 5) * NTOT + ((idx4 & 31) << 2),
                         dst + idx4 * 4);
            }
        }
        const float* sXb = sX + (ck & 1) * 4096;
#pragma unroll
        for (int k4 = 0; k4 < 8; ++k4) {   // 4 k per body
            float2 x[4];
#pragma unroll
            for (int kq = 0; kq < 4; ++kq)
                x[kq] = *(const float2*)&sXb[(k4 * 4 + kq) * 128 + n0];
#pragma unroll
            for (int o = 0; o < 8; ++o) {
                // W column base = ck*32 + k4*4  (R6 bug: ck*32 was missing)
                float4 w = *(const float4*)&sW[(ob + o) * 128 + ck * 32 + k4 * 4];
                acc[o][0] += w.x * x[0].x + w.y * x[1].x + w.z * x[2].x + w.w * x[3].x;
                acc[o][1] += w.x * x[0].y + w.y * x[1].y + w.z * x[2].y + w.w * x[3].y;
            }
        }
        if (ck < 3) __syncthreads();
    }

    // epilogue: bias + coalesced b64 store
    float* Yb = Y + (size_t)b * (CK * NTOT) + nblk + n0;
#pragma unroll
    for (int o = 0; o < 8; ++o) {
        int och = oh * 32 + ob + o;
        float bo = bias[och];
        acc[o][0] += bo; acc[o][1] += bo;
        *(float2*)&Yb[(size_t)och * NTOT] = make_float2(acc[o][0], acc[o][1]);
    }

    // fused reductions: channel och owned entirely by this wave (128 n cols)
    if (which < 2) {
        float s[8], ss[8];
#pragma unroll
        for (int o = 0; o < 8; ++o) {
            s[o]  = acc[o][0] + acc[o][1];
            ss[o] = acc[o][0] * acc[o][0] + acc[o][1] * acc[o][1];
        }
#pragma unroll
        for (int off = 32; off > 0; off >>= 1)
#pragma unroll
            for (int o = 0; o < 8; ++o) {
                s[o]  += __shfl_down(s[o],  off, 64);
                ss[o] += __shfl_down(ss[o], off, 64);
            }
        if (lane == 0) {
#pragma unroll
            for (int o = 0; o < 8; ++o) {
                int och = oh * 32 + ob + o;
                atomicAdd(&stats[which * 128 + och], s[o]);
                atomicAdd(&stats[which * 128 + 64 + och], ss[o]);
            }
        }
    } else {
        float s[8];
#pragma unroll
        for (int o = 0; o < 8; ++o) s[o] = acc[o][0] + acc[o][1];
#pragma unroll
        for (int off = 32; off > 0; off >>= 1)
#pragma unroll
            for (int o = 0; o < 8; ++o)
                s[o] += __shfl_down(s[o], off, 64);
        if (lane == 0) {
#pragma unroll
            for (int o = 0; o < 8; ++o)
                atomicAdd(&vsum[b * CV + oh * 32 + ob + o], s[o]);
        }
    }
}

// ---------------------------------------------------------------------------
// Kernel 2: KV[b,c,v] = sum_n kn[b,c,n]*V[b,v,n], kn = L2-norm(BN(Yk)).
// grid (64 n-chunks, 8 batch), block 256, split-K atomics. (R4-benched version)
// ---------------------------------------------------------------------------
__global__ __launch_bounds__(256) void kv_kernel(
    const float* __restrict__ Yk, const float* __restrict__ Vv,
    const float* __restrict__ stats,
    const float* __restrict__ gamma, const float* __restrict__ beta,
    float* __restrict__ KV)
{
    const int chunk = blockIdx.x;
    const int b     = blockIdx.y;
    __shared__ float sk[64 * 69];
    __shared__ float sv[64 * 69];
    __shared__ float rnp[4][64];
    __shared__ float rn[64];
    __shared__ float kscl[64], kshf[64];

    const int t = threadIdx.x;
    if (t < 64) {
        float S = stats[128 + t], SS = stats[192 + t];
        float mean = S * (1.f / BN_COUNT);
        float var  = SS * (1.f / BN_COUNT) - mean * mean;
        float scl = gamma[t] * rsqrtf(var + 1e-5f);
        kscl[t] = scl;
        kshf[t] = beta[t] - mean * scl;
    }
    __syncthreads();

    const int n0 = chunk * 64;
    const float* Ykb = Yk + (size_t)b * (CK * NTOT) + n0;
    const float* Vb  = Vv + (size_t)b * (CK * NTOT) + n0;

#pragma unroll
    for (int r = 0; r < 4; ++r) {
        int idx4 = t + r * 256;
        int c  = idx4 >> 4;
        int j4 = (idx4 & 15) << 2;
        float4 kf = *(const float4*)(Ykb + (size_t)c * NTOT + j4);
        float4 vf = *(const float4*)(Vb  + (size_t)c * NTOT + j4);
        float scl = kscl[c], sh = kshf[c];
        sk[c * 69 + j4 + 0] = kf.x * scl + sh;
        sk[c * 69 + j4 + 1] = kf.y * scl + sh;
        sk[c * 69 + j4 + 2] = kf.z * scl + sh;
        sk[c * 69 + j4 + 3] = kf.w * scl + sh;
        sv[c * 69 + j4 + 0] = vf.x; sv[c * 69 + j4 + 1] = vf.y;
        sv[c * 69 + j4 + 2] = vf.z; sv[c * 69 + j4 + 3] = vf.w;
    }
    __syncthreads();
    {   // column sumsq partials: wave w covers c in [16w,16w+16)
        int nn = t & 63, w = t >> 6;
        float ps = 0.f;
#pragma unroll
        for (int i = 0; i < 16; ++i) {
            float x = sk[(w * 16 + i) * 69 + nn];
            ps += x * x;
        }
        rnp[w][nn] = ps;
    }
    __syncthreads();
    if (t < 64) {
        float rs = rnp[0][t] + rnp[1][t] + rnp[2][t] + rnp[3][t];
        rn[t] = 1.f / (sqrtf(rs) + 1e-7f);
    }
    __syncthreads();

    const int tc = t >> 4, tv = t & 15;
    float acc[4][4];
#pragma unroll
    for (int i = 0; i < 4; ++i)
#pragma unroll
        for (int k2 = 0; k2 < 4; ++k2) acc[i][k2] = 0.f;

#pragma unroll 4
    for (int j = 0; j < 64; ++j) {
        float arn = rn[j];
        float a[4], bb[4];
#pragma unroll
        for (int i = 0; i < 4; ++i) a[i]  = sk[(tc * 4 + i) * 69 + j] * arn;
#pragma unroll
        for (int i = 0; i < 4; ++i) bb[i] = sv[(tv * 4 + i) * 69 + j];
#pragma unroll
        for (int i = 0; i < 4; ++i)
#pragma unroll
            for (int k2 = 0; k2 < 4; ++k2) acc[i][k2] += a[i] * bb[k2];
    }

    float* KVb = KV + b * (CK * CV);
#pragma unroll
    for (int i = 0; i < 4; ++i)
#pragma unroll
        for (int k2 = 0; k2 < 4; ++k2)
            atomicAdd(&KVb[(tc * 4 + i) * CV + tv * 4 + k2], acc[i][k2]);
}

// ---------------------------------------------------------------------------
// Kernel 3: M[b,c,o] = sum_v KV[b,c,v]*Ww[o,v];  d[b,o] = bw[o] + Ww·vsum
// grid (8 o-slices, 8 batch), block 256; each block: 64c x 16o.
// ---------------------------------------------------------------------------
__global__ __launch_bounds__(256) void m_kernel(
    const float* __restrict__ KV, const float* __restrict__ vsum,
    const float* __restrict__ Ww, const float* __restrict__ bw,
    float* __restrict__ M, float* __restrict__ d)
{
    const int och = blockIdx.x;       // 0..7, o-slice of 16
    const int b   = blockIdx.y;
    __shared__ float sKV[64 * 65];
    __shared__ float sWw[16 * 68];
    __shared__ float svs[64];
    const int t = threadIdx.x;

#pragma unroll
    for (int r = 0; r < 16; ++r) {
        int idx = t + r * 256;                       // 0..4095
        sKV[(idx >> 6) * 65 + (idx & 63)] = KV[b * (CK * CV) + idx];
    }
    {   // 16 o-rows x 64 v = 256 float4
        int o16 = t >> 4, v4 = (t & 15) << 2;
        float4 wv = *(const float4*)(Ww + (size_t)(och * 16 + o16) * CV + v4);
        *(float4*)&sWw[o16 * 68 + v4] = wv;
    }
    if (t < 64) svs[t] = vsum[b * CV + t];
    __syncthreads();

#pragma unroll
    for (int r = 0; r < 4; ++r) {
        int idx = t + r * 256;                       // 0..1023
        int c = idx >> 4, o16 = idx & 15;
        float acc = 0.f;
#pragma unroll 16
        for (int v = 0; v < 64; ++v) acc += sKV[c * 65 + v] * sWw[o16 * 68 + v];
        M[(size_t)b * (CK * CO) + (size_t)c * CO + och * 16 + o16] = acc;
    }
    if (t < 16) {
        int o = och * 16 + t;
        float acc = bw[o];
#pragma unroll 16
        for (int v = 0; v < 64; ++v) acc += sWw[t * 68 + v] * svs[v];
        d[b * CO + o] = acc;
    }
}

// ---------------------------------------------------------------------------
// Kernel 4: out[b,o,n] = rn_n * (sum_c qhat[b,c,n]*M[b,c,o]) + d[b,o]
// qhat = BN(Yq); rn applied in epilogue. (R4-benched version)
// grid (64 n-chunks, 8 batch), block 256. Thread: 4n x 8o.
// ---------------------------------------------------------------------------
__global__ __launch_bounds__(256) void out_kernel(
    const float* __restrict__ Yq,
    const float* __restrict__ stats,
    const float* __restrict__ gamma, const float* __restrict__ beta,
    const float* __restrict__ M, const float* __restrict__ d,
    float* __restrict__ out)
{
    const int chunk = blockIdx.x;
    const int b     = blockIdx.y;
    __shared__ float sM[CK * CO];     // [c][o], 32 KB
    __shared__ float sq[64 * 68];     // padded rows
    __shared__ float rnp[4][64];
    __shared__ float sd[CO];
    __shared__ float qscl[64], qshf[64];

    const int t = threadIdx.x;
    const int n0 = chunk * 64;

    if (t < 64) {
        float S = stats[t], SS = stats[64 + t];
        float mean = S * (1.f / BN_COUNT);
        float var  = SS * (1.f / BN_COUNT) - mean * mean;
        float scl = gamma[t] * rsqrtf(var + 1e-5f);
        qscl[t] = scl;
        qshf[t] = beta[t] - mean * scl;
    }
    if (t < CO) sd[t] = d[b * CO + t];
    __syncthreads();

#pragma unroll
    for (int r = 0; r < 8; ++r) {
        int idx4 = t + r * 256;
        ((float4*)sM)[idx4] = ((const float4*)(M + (size_t)b * (CK * CO)))[idx4];
    }
    const float* Yb = Yq + (size_t)b * (CK * NTOT) + n0;
#pragma unroll
    for (int r = 0; r < 4; ++r) {
        int idx4 = t + r * 256;
        int c  = idx4 >> 4;
        int j4 = (idx4 & 15) << 2;
        float4 xv = *(const float4*)(Yb + (size_t)c * NTOT + j4);
        float scl = qscl[c], sh = qshf[c];
        *(float4*)&sq[c * 68 + j4] = make_float4(
            xv.x * scl + sh, xv.y * scl + sh, xv.z * scl + sh, xv.w * scl + sh);
    }
    __syncthreads();
    {   // column sumsq partials across 4 waves
        int nn = t & 63, w = t >> 6;
        float ps = 0.f;
#pragma unroll
        for (int i = 0; i < 16; ++i) {
            float x = sq[(w * 16 + i) * 68 + nn];
            ps += x * x;
        }
        rnp[w][nn] = ps;
    }
    __syncthreads();

    const int j0 = (t & 15) << 2;       // 4 columns
    const int o0 = (t >> 4) << 3;       // 8 out-channels
    float acc[4][8];
#pragma unroll
    for (int jj = 0; jj < 4; ++jj)
#pragma unroll
        for (int oo = 0; oo < 8; ++oo) acc[jj][oo] = 0.f;

#pragma unroll 4
    for (int c = 0; c < 64; ++c) {
        float4 qv = *(const float4*)&sq[c * 68 + j0];
        float4 m0 = *(const float4*)&sM[c * CO + o0];
        float4 m1 = *(const float4*)&sM[c * CO + o0 + 4];
        float aq[4] = {qv.x, qv.y, qv.z, qv.w};
        float am[8] = {m0.x, m0.y, m0.z, m0.w, m1.x, m1.y, m1.z, m1.w};
#pragma unroll
        for (int jj = 0; jj < 4; ++jj)
#pragma unroll
            for (int oo = 0; oo < 8; ++oo) acc[jj][oo] += aq[jj] * am[oo];
    }

    float rnj[4];
#pragma unroll
    for (int jj = 0; jj < 4; ++jj) {
        int j = j0 + jj;
        float rs = rnp[0][j] + rnp[1][j] + rnp[2][j] + rnp[3][j];
        rnj[jj] = 1.f / (sqrtf(rs) + 1e-7f);
    }
    float* outb = out + (size_t)b * (CO * NTOT) + n0;
#pragma unroll
    for (int oo = 0; oo < 8; ++oo) {
        float dv = sd[o0 + oo];
        float4 st = make_float4(acc[0][oo] * rnj[0] + dv, acc[1][oo] * rnj[1] + dv,
                                acc[2][oo] * rnj[2] + dv, acc[3][oo] * rnj[3] + dv);
        *(float4*)&outb[(size_t)(o0 + oo) * NTOT + j0] = st;
    }
}

// ---------------------------------------------------------------------------
extern "C" void kernel_launch(void* const* d_in, const int* in_sizes, int n_in,
                              void* d_out, int out_size, void* d_ws, size_t ws_size,
                              hipStream_t stream) {
    (void)in_sizes; (void)n_in; (void)out_size; (void)ws_size;
    const float* q     = (const float*)d_in[0];
    const float* k     = (const float*)d_in[1];
    const float* v     = (const float*)d_in[2];
    const float* Wk    = (const float*)d_in[3];
    const float* bk    = (const float*)d_in[4];
    const float* gamma = (const float*)d_in[5];
    const float* beta  = (const float*)d_in[6];
    const float* Wv    = (const float*)d_in[7];
    const float* bv    = (const float*)d_in[8];
    const float* Ww    = (const float*)d_in[9];
    const float* bw    = (const float*)d_in[10];
    float* out = (float*)d_out;
    float* ws  = (float*)d_ws;

    float* Yq    = ws + OFF_YQ;
    float* Yk    = ws + OFF_YK;
    float* Vv    = ws + OFF_V;
    float* stats = ws + OFF_STATS;
    float* KV    = ws + OFF_KV;
    float* vsum  = ws + OFF_VSUM;
    float* M     = ws + OFF_M;
    float* dd    = ws + OFF_D;

    // zero stats + KV + vsum (contiguous; ws is re-poisoned before every call)
    hipMemsetAsync(stats, 0, ZERO_FLOATS * sizeof(float), stream);

    gemm3_kernel<<<dim3(64, NBATCH, 3), 256, 0, stream>>>(
        q, k, v, Wk, bk, Wv, bv, Yq, Yk, Vv, stats, vsum);
    kv_kernel<<<dim3(64, NBATCH), 256, 0, stream>>>(Yk, Vv, stats, gamma, beta, KV);
    m_kernel<<<dim3(8, NBATCH), 256, 0, stream>>>(KV, vsum, Ww, bw, M, dd);
    out_kernel<<<dim3(64, NBATCH), 256, 0, stream>>>(Yq, stats, gamma, beta, M, dd, out);
}